// Round 10
// baseline (2605.732 us; speedup 1.0000x reference)
//
#include <hip/hip_runtime.h>
#include <hip/hip_bf16.h>

// B=1024, L=128, W=512, S=8, STEPS=12, VOCAB=32, NLAB=10

typedef unsigned short u16;
typedef __attribute__((ext_vector_type(8))) short short8;   // 8 x bf16
typedef __attribute__((ext_vector_type(4))) float f32x4;

__device__ __forceinline__ float bf2f(u16 v) {
    union { unsigned int u; float f; } x; x.u = ((unsigned int)v) << 16; return x.f;
}
__device__ __forceinline__ u16 f2bf(float f) {
    union { float f; unsigned int u; } x; x.f = f;
    unsigned int u = x.u;
    return (u16)((u + 0x7FFFu + ((u >> 16) & 1u)) >> 16);   // RNE
}
// Fast transcendentals (HW v_exp/v_log/v_cos/v_rcp; ~1e-6 err << bf16 eps)
__device__ __forceinline__ float fsig(float v) {
    return __builtin_amdgcn_rcpf(1.f + __expf(-v));
}
__device__ __forceinline__ float ftanh(float v) {
    return 1.f - 2.f * __builtin_amdgcn_rcpf(__expf(2.f * v) + 1.f);
}
__device__ __forceinline__ float fsoftplus(float v) {
    return (v > 20.f) ? v : __logf(1.f + __expf(v));
}

union U4 { ushort4 v; u16 e[4]; };

// Async global->LDS, 16B/lane. LDS dest = wave-uniform base + lane*16.
__device__ __forceinline__ void gload_lds16(const u16* g, u16* l) {
    __builtin_amdgcn_global_load_lds(
        (const __attribute__((address_space(1))) unsigned int*)g,
        (__attribute__((address_space(3))) unsigned int*)l, 16, 0, 0);
}

// ---------------------------------------------------------------------------
// Input-dtype detection (bf16 vs f32 inputs).
// ---------------------------------------------------------------------------
__device__ __forceinline__ int sane16(u16 u) {
    if ((u & 0x7FFF) == 0) return 1;
    int e = (u >> 7) & 0xFF;
    return (e >= 0x33 && e <= 0x43) ? 1 : 0;
}
__global__ __launch_bounds__(256) void detect_k(const u16* __restrict__ raw,
                                                int* __restrict__ flag) {
    const int t = threadIdx.x;
    int c = sane16(raw[1024 + t * 2]) + sane16(raw[1024 + t * 2 + 1]);
#pragma unroll
    for (int off = 32; off; off >>= 1) c += __shfl_down(c, off, 64);
    __shared__ int red[4];
    if ((t & 63) == 0) red[t >> 6] = c;
    __syncthreads();
    if (t == 0) *flag = (red[0] + red[1] + red[2] + red[3] >= 448) ? 1 : 0;
}

// ---------------------------------------------------------------------------
// Canonicalize float tensors to bf16, vectorized.
// ---------------------------------------------------------------------------
struct CT { const void* src[20]; int n[20]; int off[20]; };
__global__ __launch_bounds__(256) void conv_k(CT ct, u16* __restrict__ dstBase,
                                              const int* __restrict__ flag) {
    const int isbf = *flag;
    const int gid = blockIdx.x * 256 + threadIdx.x;
    const int stride = gridDim.x * 256;
    for (int tn = 0; tn < 20; ++tn) {
        const int n = ct.n[tn];
        const int n4 = n >> 2;
        u16* dst = dstBase + ct.off[tn];
        if (!isbf) {
            const float* s = (const float*)ct.src[tn];
            for (int i = gid; i < n4; i += stride) {
                f32x4 v = *(const f32x4*)(s + i * 4);
                *(ushort4*)(dst + i * 4) =
                    make_ushort4(f2bf(v[0]), f2bf(v[1]), f2bf(v[2]), f2bf(v[3]));
            }
            if (gid < (n & 3)) { int i = n4 * 4 + gid; dst[i] = f2bf(s[i]); }
        } else {
            const u16* s = (const u16*)ct.src[tn];
            for (int i = gid; i < n4; i += stride)
                *(ushort4*)(dst + i * 4) = *(const ushort4*)(s + i * 4);
            if (gid < (n & 3)) { int i = n4 * 4 + gid; dst[i] = s[i]; }
        }
    }
}

// ---------------------------------------------------------------------------
// Pack Wcat[s][g][0:512]=W_ih[s][g][:], [512:1024]=W_hh[s][g][:]  (one-time)
// ---------------------------------------------------------------------------
__global__ __launch_bounds__(256) void pack_k(const u16* __restrict__ Wih,
                                              const u16* __restrict__ Whh,
                                              u16* __restrict__ Wcat) {
    long i = ((long)blockIdx.x * 256 + threadIdx.x) * 8;   // over 8*1536*512
    if (i >= 8L * 1536 * 512) return;
    long sg = i >> 9;
    long k  = i & 511;
    *(short8*)(Wcat + sg * 1024 + k)       = *(const short8*)(Wih + i);
    *(short8*)(Wcat + sg * 1024 + 512 + k) = *(const short8*)(Whh + i);
}

// ---------------------------------------------------------------------------
// Batched GEMM, MT x 128 tile, BK=64, single-barrier LDS double-buffer with
// global_load_lds staging (R7-proven structure).
// ---------------------------------------------------------------------------
struct GP {
    const u16* A;  long lda; long aOff[8];
    const u16* Bw; long ldb; long bwOff[8];
    const u16* bias; long biasOff[8];
    const u16* add; long ldadd; long addOff;
    void* C; long ldc; long cOff[8];
    float* C2;                                  // EPI 4
    u16* C3;                                    // EPI 4
    int K; int nt;
};

template<int EPI, int MT>
__global__ __launch_bounds__(256) void gemm_k(GP p) {
    constexpr int MW   = MT / 32;
    constexpr int AITS = MT / 32;
    __shared__ __align__(16) u16 lA[2][MT * 64];
    __shared__ __align__(16) u16 lB[2][128 * 64];
    const int t    = threadIdx.x;
    const int lane = t & 63;
    const int wv   = t >> 6;
    const int bx   = blockIdx.x;
    const int z    = bx / p.nt;
    const int n0   = (bx - z * p.nt) * 128;
    const int m0   = blockIdx.y * MT;

    const u16* Ab = p.A + p.aOff[z] + (long)m0 * p.lda;
    const u16* Bb = p.Bw + p.bwOff[z] + (long)n0 * p.ldb;

    f32x4 acc[MW][4];
#pragma unroll
    for (int i = 0; i < MW; i++)
#pragma unroll
        for (int j = 0; j < 4; j++) acc[i][j] = (f32x4){0.f, 0.f, 0.f, 0.f};

    const int wm   = (wv & 1) * (MT / 2);
    const int wn   = (wv >> 1) * 64;
    const int fr   = lane & 15;
    const int quad = lane >> 4;

    const int nk = p.K >> 6;
#pragma unroll
    for (int it = 0; it < AITS; ++it) {
        int flat = it * 256 + t, row = flat >> 3, src = (flat & 7) ^ (row & 7);
        gload_lds16(Ab + (long)row * p.lda + src * 8, &lA[0][flat * 8]);
    }
#pragma unroll
    for (int it = 0; it < 4; ++it) {
        int flat = it * 256 + t, row = flat >> 3, src = (flat & 7) ^ (row & 7);
        gload_lds16(Bb + (long)row * p.ldb + src * 8, &lB[0][flat * 8]);
    }
    __syncthreads();

    for (int kt = 0; kt < nk; ++kt) {
        const int cur = kt & 1, nxt = cur ^ 1;
        if (kt + 1 < nk) {
            const long kb = (long)(kt + 1) * 64;
#pragma unroll
            for (int it = 0; it < AITS; ++it) {
                int flat = it * 256 + t, row = flat >> 3, src = (flat & 7) ^ (row & 7);
                gload_lds16(Ab + (long)row * p.lda + kb + src * 8, &lA[nxt][flat * 8]);
            }
#pragma unroll
            for (int it = 0; it < 4; ++it) {
                int flat = it * 256 + t, row = flat >> 3, src = (flat & 7) ^ (row & 7);
                gload_lds16(Bb + (long)row * p.ldb + kb + src * 8, &lB[nxt][flat * 8]);
            }
        }
#pragma unroll
        for (int kk = 0; kk < 2; ++kk) {
            const int q = kk * 4 + quad;
            short8 aF[MW], bF[4];
#pragma unroll
            for (int mi = 0; mi < MW; mi++) {
                int row = wm + mi * 16 + fr;
                aF[mi] = *(const short8*)&lA[cur][row * 64 + (q ^ (row & 7)) * 8];
            }
#pragma unroll
            for (int ni = 0; ni < 4; ni++) {
                int row = wn + ni * 16 + fr;
                bF[ni] = *(const short8*)&lB[cur][row * 64 + (q ^ (row & 7)) * 8];
            }
#pragma unroll
            for (int mi = 0; mi < MW; mi++)
#pragma unroll
                for (int ni = 0; ni < 4; ni++)
                    acc[mi][ni] = __builtin_amdgcn_mfma_f32_16x16x32_bf16(
                        aF[mi], bF[ni], acc[mi][ni], 0, 0, 0);
        }
        __syncthreads();
    }

    // Epilogue: D row = quad*4+reg, col = lane&15
#pragma unroll
    for (int mi = 0; mi < MW; mi++) {
#pragma unroll
        for (int ni = 0; ni < 4; ni++) {
            const int mg = m0 + wm + mi * 16 + quad * 4;
            const int ng = n0 + wn + ni * 16 + fr;
#pragma unroll
            for (int r = 0; r < 4; r++) {
                float v = acc[mi][ni][r];
                const long row = mg + r;
                if (EPI == 1) {        // tanh(acc+add+bias) -> bf16   [link->fhs]
                    float ad = bf2f(p.add[z * p.addOff + row * p.ldadd + ng]);
                    v = ftanh(v + ad + bf2f(p.bias[p.biasOff[z] + ng]));
                    ((u16*)p.C)[p.cOff[z] + row * p.ldc + ng] = f2bf(v);
                } else if (EPI == 4) { // encode mix: h_b, summ_b, h(f32)
                    v = ftanh(v + bf2f(p.bias[ng]));
                    u16 b = f2bf(v);
                    ((u16*)p.C)[row * 512 + ng] = b;
                    p.C3[row * 512 + ng] = b;
                    p.C2[row * 512 + ng] = v;
                } else if (EPI == 6) { // (acc+bias) -> bf16            [cin]
                    v = v + bf2f(p.bias[p.biasOff[z] + ng]);
                    ((u16*)p.C)[p.cOff[z] + row * p.ldc + ng] = f2bf(v);
                } else {               // EPI 7: tanh(acc+add) -> bf16  [f0]
                    float ad = bf2f(p.add[row * p.ldadd + ng]);
                    v = ftanh(v + ad);
                    ((u16*)p.C)[row * p.ldc + ng] = f2bf(v);
                }
            }
        }
    }
}

// ---------------------------------------------------------------------------
// Fused GRU-GEMM, NI=1 variant: block = (64 b-rows, s, 64 w-cols).
// LDS 32 KB (was 56) -> 4-5 blocks/CU for latency overlap (R9 was 2/CU).
// Swizzle f(row)=(row>>1)&3 (R9-verified conflict-free).
// ---------------------------------------------------------------------------
struct GGP {
    const u16* fhs_in;    // [b][s][1024]  (feats | hs_b)
    u16* fhs_out;         // write hs_b' at [b][s][512+w]
    const u16* Wcat;      // [s][1536][1024]
    const u16* b_ih;      // [s][1536]
    const u16* b_hh;      // [s][1536]
    u16* prism;           // [b][s][512]
    float* gate_pre;      // [b][8]  (atomicAdd, pre-zeroed)
    const u16* Wg;        // [s][512]
    const u16* phase;     // [s][512]
    const u16* pgain;     // [s][512]
};

__global__ __launch_bounds__(256) void grug_k(GGP p) {
    __shared__ __align__(16) u16 sA[2][64 * 32];        //  8 KB
    __shared__ __align__(16) u16 sW[2][3][64 * 32];     // 24 KB
    const int t    = threadIdx.x;
    const int lane = t & 63;
    const int wv   = t >> 6;
    const int s    = blockIdx.x >> 3;
    const int w0   = (blockIdx.x & 7) * 64;
    const int m0   = blockIdx.y * 64;
    const int fr   = lane & 15;
    const int quad = lane >> 4;
    const int wn   = wv * 16;          // wave's 16-col n-range

    const u16* Ab = p.fhs_in + (long)m0 * 8192 + s * 1024;
    const u16* Wb = p.Wcat + (long)s * 1536 * 1024;

    f32x4 acc[4][4];   // [q: r,z,inn,hn][mi]
#pragma unroll
    for (int q = 0; q < 4; q++)
#pragma unroll
        for (int mi = 0; mi < 4; mi++) acc[q][mi] = (f32x4){0.f,0.f,0.f,0.f};

    const int arow = t >> 2, asrc = (t & 3) ^ ((arow >> 1) & 3);

    auto stageA = [&](int buf, long kb) {
        gload_lds16(Ab + (long)arow * 8192 + kb + asrc * 8, &sA[buf][t * 8]);
    };
    auto stageW = [&](int buf, long kb) {
#pragma unroll
        for (int q = 0; q < 3; q++) {
            long g = (long)(q * 512 + w0 + arow);
            gload_lds16(Wb + g * 1024 + kb + asrc * 8, &sW[buf][q][t * 8]);
        }
    };

    stageA(0, 0); stageW(0, 0);
    __syncthreads();

    for (int kt = 0; kt < 32; ++kt) {
        const int cur = kt & 1, nxt = cur ^ 1;
        if (kt + 1 < 32) { stageA(nxt, (long)(kt + 1) * 32); stageW(nxt, (long)(kt + 1) * 32); }
        const int qsel = (kt < 16) ? 2 : 3;   // inn (k<512) vs hn (k>=512)
        short8 aF[4], bFq[3];
#pragma unroll
        for (int mi = 0; mi < 4; mi++) {
            int row = mi * 16 + fr;
            aF[mi] = *(const short8*)&sA[cur][row * 32 + ((quad ^ ((row >> 1) & 3)) & 3) * 8];
        }
        {
            int row = wn + fr;
            int sw = ((quad ^ ((row >> 1) & 3)) & 3) * 8;
#pragma unroll
            for (int q = 0; q < 3; q++)
                bFq[q] = *(const short8*)&sW[cur][q][row * 32 + sw];
        }
#pragma unroll
        for (int mi = 0; mi < 4; mi++) {
            acc[0][mi] = __builtin_amdgcn_mfma_f32_16x16x32_bf16(aF[mi], bFq[0], acc[0][mi], 0, 0, 0);
            acc[1][mi] = __builtin_amdgcn_mfma_f32_16x16x32_bf16(aF[mi], bFq[1], acc[1][mi], 0, 0, 0);
            if (qsel == 2)
                acc[2][mi] = __builtin_amdgcn_mfma_f32_16x16x32_bf16(aF[mi], bFq[2], acc[2][mi], 0, 0, 0);
            else
                acc[3][mi] = __builtin_amdgcn_mfma_f32_16x16x32_bf16(aF[mi], bFq[2], acc[3][mi], 0, 0, 0);
        }
        __syncthreads();
    }

    // Epilogue: single col per thread; params loaded once.
    const u16* bih = p.b_ih + (long)s * 1536;
    const u16* bhh = p.b_hh + (long)s * 1536;
    const int col = w0 + wn + fr;
    const float br  = bf2f(bih[col])        + bf2f(bhh[col]);
    const float bz  = bf2f(bih[512 + col])  + bf2f(bhh[512 + col]);
    const float bin = bf2f(bih[1024 + col]);
    const float bhn = bf2f(bhh[1024 + col]);
    const float ph  = bf2f(p.phase[s * 512 + col]);
    const float gain = fsoftplus(bf2f(p.pgain[s * 512 + col]));
    const float wg  = bf2f(p.Wg[s * 512 + col]);

    float gp[4][4];
#pragma unroll
    for (int mi = 0; mi < 4; mi++) {
#pragma unroll
        for (int r = 0; r < 4; r++) {
            const long b = m0 + mi * 16 + quad * 4 + r;
            float rv = fsig(acc[0][mi][r] + br);
            float zv = fsig(acc[1][mi][r] + bz);
            float nv = ftanh(acc[2][mi][r] + bin + rv * (acc[3][mi][r] + bhn));
            float hold = bf2f(p.fhs_in[b * 8192 + s * 1024 + 512 + col]);
            float hv = (1.f - zv) * nv + zv * hold;
            p.fhs_out[b * 8192 + s * 1024 + 512 + col] = f2bf(hv);
            float c = __cosf(hv + ph);
            p.prism[b * 4096 + s * 512 + col] = f2bf(c * c * gain);
            gp[mi][r] = wg * hv;
        }
    }
#pragma unroll
    for (int m = 1; m < 16; m <<= 1)
#pragma unroll
        for (int mi = 0; mi < 4; mi++)
#pragma unroll
            for (int r = 0; r < 4; r++) gp[mi][r] += __shfl_xor(gp[mi][r], m, 64);
    if (fr == 0) {
#pragma unroll
        for (int mi = 0; mi < 4; mi++)
#pragma unroll
            for (int r = 0; r < 4; r++) {
                long b = m0 + mi * 16 + quad * 4 + r;
                atomicAdd(&p.gate_pre[b * 8 + s], gp[mi][r]);
            }
    }
}

// ---------------------------------------------------------------------------
// Fused upd-GEMM + h-update: block = (64 b, 128 w), loops all 8 s (64 k-iters
// deep pipeline); per-s fold sig(gate)*tanh(acc+bias) into f32 dsum; epilogue
// h = tanh(h*decay + dsum/sqrt(8)).  Replaces upd GEMM + hupd (16 MB/step).
// ---------------------------------------------------------------------------
struct UP {
    const u16* prism;      // [b][4096]
    const u16* Wd;         // [s][512][512]
    const u16* bd;         // [s][512]
    const float* gate_pre; // [b][8]
    const u16* bgate;      // [8]
    float* h; u16* h_b;
    const u16* decayp;
};

__global__ __launch_bounds__(256) void updh_k(UP p) {
    __shared__ __align__(16) u16 lA[2][64 * 64];    // 16 KB
    __shared__ __align__(16) u16 lB[2][128 * 64];   // 32 KB
    const int t    = threadIdx.x;
    const int lane = t & 63;
    const int wv   = t >> 6;
    const int n0   = blockIdx.x * 128;
    const int m0   = blockIdx.y * 64;
    const int wm   = (wv & 1) * 32;
    const int wn   = (wv >> 1) * 64;
    const int fr   = lane & 15;
    const int quad = lane >> 4;

    f32x4 acc[2][4], dsum[2][4];
#pragma unroll
    for (int i = 0; i < 2; i++)
#pragma unroll
        for (int j = 0; j < 4; j++) { acc[i][j] = (f32x4){0.f,0.f,0.f,0.f}; dsum[i][j] = (f32x4){0.f,0.f,0.f,0.f}; }

    auto stageA = [&](int buf, int z, long kb) {
        const u16* Ab = p.prism + (long)m0 * 4096 + z * 512;
#pragma unroll
        for (int it = 0; it < 2; ++it) {
            int flat = it * 256 + t, row = flat >> 3, src = (flat & 7) ^ (row & 7);
            gload_lds16(Ab + (long)row * 4096 + kb + src * 8, &lA[buf][flat * 8]);
        }
    };
    auto stageB = [&](int buf, int z, long kb) {
        const u16* Bb = p.Wd + (long)z * 512 * 512 + (long)n0 * 512;
#pragma unroll
        for (int it = 0; it < 4; ++it) {
            int flat = it * 256 + t, row = flat >> 3, src = (flat & 7) ^ (row & 7);
            gload_lds16(Bb + (long)row * 512 + kb + src * 8, &lB[buf][flat * 8]);
        }
    };

    stageA(0, 0, 0); stageB(0, 0, 0);
    __syncthreads();
    const float decay = fsig(bf2f(p.decayp[0]));

    for (int g = 0; g < 64; ++g) {
        const int cur = g & 1, nxt = cur ^ 1;
        if (g + 1 < 64) {
            int z2 = (g + 1) >> 3; long k2 = (long)((g + 1) & 7) * 64;
            stageA(nxt, z2, k2); stageB(nxt, z2, k2);
        }
#pragma unroll
        for (int kk = 0; kk < 2; ++kk) {
            const int q = kk * 4 + quad;
            short8 aF[2], bF[4];
#pragma unroll
            for (int mi = 0; mi < 2; mi++) {
                int row = wm + mi * 16 + fr;
                aF[mi] = *(const short8*)&lA[cur][row * 64 + (q ^ (row & 7)) * 8];
            }
#pragma unroll
            for (int ni = 0; ni < 4; ni++) {
                int row = wn + ni * 16 + fr;
                bF[ni] = *(const short8*)&lB[cur][row * 64 + (q ^ (row & 7)) * 8];
            }
#pragma unroll
            for (int mi = 0; mi < 2; mi++)
#pragma unroll
                for (int ni = 0; ni < 4; ni++)
                    acc[mi][ni] = __builtin_amdgcn_mfma_f32_16x16x32_bf16(
                        aF[mi], bF[ni], acc[mi][ni], 0, 0, 0);
        }
        if ((g & 7) == 7) {                      // fold pocket z into dsum
            const int z = g >> 3;
            const float bgz = bf2f(p.bgate[z]);
            float sg[2][4];
#pragma unroll
            for (int mi = 0; mi < 2; mi++)
#pragma unroll
                for (int r = 0; r < 4; r++) {
                    long row = m0 + wm + mi * 16 + quad * 4 + r;
                    sg[mi][r] = fsig(p.gate_pre[row * 8 + z] + bgz);
                }
#pragma unroll
            for (int ni = 0; ni < 4; ni++) {
                const int col = n0 + wn + ni * 16 + fr;
                const float bdz = bf2f(p.bd[z * 512 + col]);
#pragma unroll
                for (int mi = 0; mi < 2; mi++)
#pragma unroll
                    for (int r = 0; r < 4; r++) {
                        dsum[mi][ni][r] += ftanh(acc[mi][ni][r] + bdz) * sg[mi][r];
                        acc[mi][ni][r] = 0.f;
                    }
            }
        }
        __syncthreads();
    }

    // h update
#pragma unroll
    for (int mi = 0; mi < 2; mi++)
#pragma unroll
        for (int ni = 0; ni < 4; ni++) {
            const int col = n0 + wn + ni * 16 + fr;
#pragma unroll
            for (int r = 0; r < 4; r++) {
                long row = m0 + wm + mi * 16 + quad * 4 + r;
                long idx = row * 512 + col;
                float hv = ftanh(p.h[idx] * decay + dsum[mi][ni][r] * 0.35355339059327373f);
                p.h[idx] = hv;
                p.h_b[idx] = f2bf(hv);
            }
        }
}

// ---------------------------------------------------------------------------
// Encode: masked mean / masked max / last token -> cat [B,1536]
// ---------------------------------------------------------------------------
__global__ __launch_bounds__(256) void encode_k(const int* __restrict__ x,
                                                const u16* __restrict__ embed,
                                                u16* __restrict__ cat) {
    __shared__ int toks[128];
    __shared__ int cnt_s;
    const int b = blockIdx.x, t = threadIdx.x;
    if (t < 128) toks[t] = x[b * 128 + t];
    __syncthreads();
    if (t == 0) {
        int c = 0;
        for (int l = 0; l < 128; l++) c += (toks[l] != 0);
        cnt_s = c;
    }
    __syncthreads();
    const int cnt = cnt_s;
    const int lastTok = toks[cnt > 0 ? cnt - 1 : 0];
    for (int w = t; w < 512; w += 256) {
        float sum = 0.f, mx = -10000.f;
        for (int l = 0; l < 128; l++) {
            int tok = toks[l];
            if (tok != 0) {
                float e = bf2f(embed[tok * 512 + w]);
                sum += e;
                mx = fmaxf(mx, e);
            }
        }
        float mean = sum / (float)(cnt > 0 ? cnt : 1);
        float last = bf2f(embed[lastTok * 512 + w]);
        cat[(long)b * 1536 + w]        = f2bf(mean);
        cat[(long)b * 1536 + 512 + w]  = f2bf(mx);
        cat[(long)b * 1536 + 1024 + w] = f2bf(last);
    }
}

// ---------------------------------------------------------------------------
// Final head; output dtype follows detected input dtype.
// ---------------------------------------------------------------------------
__global__ __launch_bounds__(64) void out_k(const float* __restrict__ h,
                                            const u16* __restrict__ Wout,
                                            const u16* __restrict__ bout,
                                            void* __restrict__ out,
                                            const int* __restrict__ flag) {
    const int b = blockIdx.x, lane = threadIdx.x;
    const int isbf = *flag;
    for (int j = 0; j < 10; j++) {
        float p = 0.f;
#pragma unroll
        for (int k = 0; k < 8; k++) {
            int w = lane + k * 64;
            p += h[(long)b * 512 + w] * bf2f(Wout[j * 512 + w]);
        }
#pragma unroll
        for (int off = 32; off; off >>= 1) p += __shfl_down(p, off, 64);
        if (lane == 0) {
            float val = p + bf2f(bout[j]);
            if (isbf) ((u16*)out)[b * 10 + j] = f2bf(val);
            else      ((float*)out)[b * 10 + j] = val;
        }
    }
}

// ---------------------------------------------------------------------------
extern "C" void kernel_launch(void* const* d_in, const int* in_sizes, int n_in,
                              void* d_out, int out_size, void* d_ws, size_t ws_size,
                              hipStream_t stream) {
    (void)n_in; (void)out_size; (void)ws_size;
    const int* x = (const int*)d_in[0];

    char* pp = (char*)d_ws;
    auto carve = [&](size_t n) { char* r = pp; pp += (n + 255) & ~(size_t)255; return (void*)r; };

    // canonical bf16 parameter block (~44 MB)
    CT ct;
    size_t ctot = 0;
    for (int i = 0; i < 20; i++) {
        ct.src[i] = d_in[i + 1];
        ct.n[i]   = in_sizes[i + 1];
        ct.off[i] = (int)ctot;
        ctot += ((size_t)in_sizes[i + 1] + 15) & ~(size_t)15;
    }
    u16* canon = (u16*)carve(ctot * 2);
    const u16* embed  = canon + ct.off[0];
    const u16* W_mix  = canon + ct.off[1];
    const u16* b_mix  = canon + ct.off[2];
    const u16* W_in   = canon + ct.off[3];
    const u16* b_in   = canon + ct.off[4];
    const u16* W_link = canon + ct.off[5];
    const u16* b_link = canon + ct.off[6];
    const u16* W_ih   = canon + ct.off[7];
    const u16* b_ih   = canon + ct.off[8];
    const u16* W_hh   = canon + ct.off[9];
    const u16* b_hh   = canon + ct.off[10];
    const u16* W_gate = canon + ct.off[11];
    const u16* b_gate = canon + ct.off[12];
    const u16* phase  = canon + ct.off[13];
    const u16* pgain  = canon + ct.off[14];
    const u16* W_delta= canon + ct.off[15];
    const u16* b_delta= canon + ct.off[16];
    const u16* decayp = canon + ct.off[17];
    const u16* W_out  = canon + ct.off[18];
    const u16* b_out  = canon + ct.off[19];

    int*   flag   = (int*)  carve(256);
    u16*   Wcat   = (u16*)  carve((size_t)8 * 1536 * 1024 * 2);  // 25 MB
    u16*   cat    = (u16*)  carve((size_t)1024 * 1536 * 2);
    u16*   h_b    = (u16*)  carve((size_t)1024 * 512 * 2);
    u16*   summ_b = (u16*)  carve((size_t)1024 * 512 * 2);
    float* h      = (float*)carve((size_t)1024 * 512 * 4);
    u16*   cin    = (u16*)  carve((size_t)1024 * 4096 * 2);
    u16*   f0     = (u16*)  carve((size_t)1024 * 4096 * 2);
    u16*   fhs0   = (u16*)  carve((size_t)1024 * 8192 * 2);      // 16 MB
    u16*   fhs1   = (u16*)  carve((size_t)1024 * 8192 * 2);      // 16 MB
    u16*   prism  = (u16*)  carve((size_t)1024 * 4096 * 2);
    float* gate_pre = (float*)carve((size_t)1024 * 8 * 4);

    (void)hipMemsetAsync(fhs0, 0, (size_t)1024 * 8192 * 2, stream);
    (void)hipMemsetAsync(fhs1, 0, (size_t)1024 * 8192 * 2, stream);

    detect_k<<<dim3(1), dim3(256), 0, stream>>>((const u16*)d_in[1], flag);
    conv_k<<<dim3(1024), dim3(256), 0, stream>>>(ct, canon, flag);
    pack_k<<<dim3(3072), dim3(256), 0, stream>>>(W_ih, W_hh, Wcat);
    encode_k<<<dim3(1024), dim3(256), 0, stream>>>(x, embed, cat);

    {   // summary = tanh(cat @ W_mix^T + b_mix) -> h_b, summ_b, h
        GP p{}; p.A = cat; p.lda = 1536; p.Bw = W_mix; p.ldb = 1536;
        p.bias = b_mix; p.C = h_b; p.ldc = 512; p.C2 = h; p.C3 = summ_b;
        p.K = 1536; p.nt = 4;
        gemm_k<4, 64><<<dim3(4, 16, 1), dim3(256), 0, stream>>>(p);
    }
    {   // cin = summary @ W_in[:, :, 512:]^T + b_in
        GP p{}; p.A = summ_b; p.lda = 512; p.Bw = W_in + 512; p.ldb = 1024;
        p.bias = b_in; p.C = cin; p.ldc = 4096; p.K = 512; p.nt = 32;
        gemm_k<6, 64><<<dim3(32, 16, 1), dim3(256), 0, stream>>>(p);
    }

    for (int step = 0; step < 12; ++step) {
        u16* fhs_cur = (step & 1) ? fhs1 : fhs0;
        u16* fhs_nxt = (step & 1) ? fhs0 : fhs1;
        {   // f0 = tanh(h @ W_in[:, :, :512]^T + cin)
            GP p{}; p.A = h_b; p.lda = 512; p.Bw = W_in; p.ldb = 1024;
            p.add = cin; p.ldadd = 4096; p.C = f0; p.ldc = 4096;
            p.K = 512; p.nt = 32;
            gemm_k<7, 64><<<dim3(32, 16, 1), dim3(256), 0, stream>>>(p);
        }
        {   // feats = tanh(f0 + prev @ W_link^T + b_link) -> fhs_cur[:, s, 0:512]
            GP p{}; p.A = f0; p.lda = 4096;
            for (int s = 0; s < 8; s++) p.aOff[s] = (long)((s + 7) & 7) * 512;
            p.Bw = W_link; p.ldb = 512;
            for (int s = 0; s < 8; s++) p.bwOff[s] = (long)s * 512 * 512;
            p.bias = b_link;
            for (int s = 0; s < 8; s++) p.biasOff[s] = (long)s * 512;
            p.add = f0; p.ldadd = 4096; p.addOff = 512;
            p.C = fhs_cur; p.ldc = 8192;
            for (int s = 0; s < 8; s++) p.cOff[s] = (long)s * 1024;
            p.K = 512; p.nt = 4;
            gemm_k<1, 64><<<dim3(32, 16, 1), dim3(256), 0, stream>>>(p);
        }
        (void)hipMemsetAsync(gate_pre, 0, (size_t)1024 * 8 * 4, stream);
        {   // fused GRU-GEMM (NI=1: 64-col w-blocks, 32 KB LDS)
            GGP g{};
            g.fhs_in = fhs_cur; g.fhs_out = fhs_nxt; g.Wcat = Wcat;
            g.b_ih = b_ih; g.b_hh = b_hh; g.prism = prism; g.gate_pre = gate_pre;
            g.Wg = W_gate; g.phase = phase; g.pgain = pgain;
            grug_k<<<dim3(64, 16, 1), dim3(256), 0, stream>>>(g);
        }
        {   // fused upd-GEMM + h update
            UP u{};
            u.prism = prism; u.Wd = W_delta; u.bd = b_delta;
            u.gate_pre = gate_pre; u.bgate = b_gate;
            u.h = h; u.h_b = h_b; u.decayp = decayp;
            updh_k<<<dim3(4, 16, 1), dim3(256), 0, stream>>>(u);
        }
    }

    out_k<<<dim3(1024), dim3(64), 0, stream>>>(h, W_out, b_out, d_out, flag);
}

// Round 11
// 1998.937 us; speedup vs baseline: 1.3036x; 1.3036x over previous
//
#include <hip/hip_runtime.h>
#include <hip/hip_bf16.h>

// B=1024, L=128, W=512, S=8, STEPS=12, VOCAB=32, NLAB=10

typedef unsigned short u16;
typedef __attribute__((ext_vector_type(8))) short short8;   // 8 x bf16
typedef __attribute__((ext_vector_type(4))) float f32x4;

__device__ __forceinline__ float bf2f(u16 v) {
    union { unsigned int u; float f; } x; x.u = ((unsigned int)v) << 16; return x.f;
}
__device__ __forceinline__ u16 f2bf(float f) {
    union { float f; unsigned int u; } x; x.f = f;
    unsigned int u = x.u;
    return (u16)((u + 0x7FFFu + ((u >> 16) & 1u)) >> 16);   // RNE
}
// Fast transcendentals (HW v_exp/v_log/v_cos/v_rcp; ~1e-6 err << bf16 eps)
__device__ __forceinline__ float fsig(float v) {
    return __builtin_amdgcn_rcpf(1.f + __expf(-v));
}
__device__ __forceinline__ float ftanh(float v) {
    return 1.f - 2.f * __builtin_amdgcn_rcpf(__expf(2.f * v) + 1.f);
}
__device__ __forceinline__ float fsoftplus(float v) {
    return (v > 20.f) ? v : __logf(1.f + __expf(v));
}

union U4 { ushort4 v; u16 e[4]; };

// Async global->LDS, 16B/lane. LDS dest = wave-uniform base + lane*16.
__device__ __forceinline__ void gload_lds16(const u16* g, u16* l) {
    __builtin_amdgcn_global_load_lds(
        (const __attribute__((address_space(1))) unsigned int*)g,
        (__attribute__((address_space(3))) unsigned int*)l, 16, 0, 0);
}

// ---------------------------------------------------------------------------
// Input-dtype detection (bf16 vs f32 inputs).
// ---------------------------------------------------------------------------
__device__ __forceinline__ int sane16(u16 u) {
    if ((u & 0x7FFF) == 0) return 1;
    int e = (u >> 7) & 0xFF;
    return (e >= 0x33 && e <= 0x43) ? 1 : 0;
}
__global__ __launch_bounds__(256) void detect_k(const u16* __restrict__ raw,
                                                int* __restrict__ flag) {
    const int t = threadIdx.x;
    int c = sane16(raw[1024 + t * 2]) + sane16(raw[1024 + t * 2 + 1]);
#pragma unroll
    for (int off = 32; off; off >>= 1) c += __shfl_down(c, off, 64);
    __shared__ int red[4];
    if ((t & 63) == 0) red[t >> 6] = c;
    __syncthreads();
    if (t == 0) *flag = (red[0] + red[1] + red[2] + red[3] >= 448) ? 1 : 0;
}

// ---------------------------------------------------------------------------
// Canonicalize float tensors to bf16, vectorized.
// ---------------------------------------------------------------------------
struct CT { const void* src[20]; int n[20]; int off[20]; };
__global__ __launch_bounds__(256) void conv_k(CT ct, u16* __restrict__ dstBase,
                                              const int* __restrict__ flag) {
    const int isbf = *flag;
    const int gid = blockIdx.x * 256 + threadIdx.x;
    const int stride = gridDim.x * 256;
    for (int tn = 0; tn < 20; ++tn) {
        const int n = ct.n[tn];
        const int n4 = n >> 2;
        u16* dst = dstBase + ct.off[tn];
        if (!isbf) {
            const float* s = (const float*)ct.src[tn];
            for (int i = gid; i < n4; i += stride) {
                f32x4 v = *(const f32x4*)(s + i * 4);
                *(ushort4*)(dst + i * 4) =
                    make_ushort4(f2bf(v[0]), f2bf(v[1]), f2bf(v[2]), f2bf(v[3]));
            }
            if (gid < (n & 3)) { int i = n4 * 4 + gid; dst[i] = f2bf(s[i]); }
        } else {
            const u16* s = (const u16*)ct.src[tn];
            for (int i = gid; i < n4; i += stride)
                *(ushort4*)(dst + i * 4) = *(const ushort4*)(s + i * 4);
            if (gid < (n & 3)) { int i = n4 * 4 + gid; dst[i] = s[i]; }
        }
    }
}

// ---------------------------------------------------------------------------
// Pack Wcat[s][g][0:512]=W_ih[s][g][:], [512:1024]=W_hh[s][g][:]  (one-time)
// ---------------------------------------------------------------------------
__global__ __launch_bounds__(256) void pack_k(const u16* __restrict__ Wih,
                                              const u16* __restrict__ Whh,
                                              u16* __restrict__ Wcat) {
    long i = ((long)blockIdx.x * 256 + threadIdx.x) * 8;   // over 8*1536*512
    if (i >= 8L * 1536 * 512) return;
    long sg = i >> 9;
    long k  = i & 511;
    *(short8*)(Wcat + sg * 1024 + k)       = *(const short8*)(Wih + i);
    *(short8*)(Wcat + sg * 1024 + 512 + k) = *(const short8*)(Whh + i);
}

// ---------------------------------------------------------------------------
// Batched GEMM, MT x 128 tile, BK=64, single-barrier LDS double-buffer with
// global_load_lds staging (R7-proven structure).
// ---------------------------------------------------------------------------
struct GP {
    const u16* A;  long lda; long aOff[8];
    const u16* Bw; long ldb; long bwOff[8];
    const u16* bias; long biasOff[8];
    const u16* add; long ldadd; long addOff;
    const float* gate_pre;                      // EPI 3
    const u16* bgate;                           // EPI 3
    void* C; long ldc; long cOff[8];
    float* C2;                                  // EPI 4
    u16* C3;                                    // EPI 4
    int K; int nt;
};

template<int EPI, int MT>
__global__ __launch_bounds__(256) void gemm_k(GP p) {
    constexpr int MW   = MT / 32;
    constexpr int AITS = MT / 32;
    __shared__ __align__(16) u16 lA[2][MT * 64];
    __shared__ __align__(16) u16 lB[2][128 * 64];
    const int t    = threadIdx.x;
    const int lane = t & 63;
    const int wv   = t >> 6;
    const int bx   = blockIdx.x;
    const int z    = bx / p.nt;
    const int n0   = (bx - z * p.nt) * 128;
    const int m0   = blockIdx.y * MT;

    const u16* Ab = p.A + p.aOff[z] + (long)m0 * p.lda;
    const u16* Bb = p.Bw + p.bwOff[z] + (long)n0 * p.ldb;

    f32x4 acc[MW][4];
#pragma unroll
    for (int i = 0; i < MW; i++)
#pragma unroll
        for (int j = 0; j < 4; j++) acc[i][j] = (f32x4){0.f, 0.f, 0.f, 0.f};

    const int wm   = (wv & 1) * (MT / 2);
    const int wn   = (wv >> 1) * 64;
    const int fr   = lane & 15;
    const int quad = lane >> 4;

    const int nk = p.K >> 6;
#pragma unroll
    for (int it = 0; it < AITS; ++it) {
        int flat = it * 256 + t, row = flat >> 3, src = (flat & 7) ^ (row & 7);
        gload_lds16(Ab + (long)row * p.lda + src * 8, &lA[0][flat * 8]);
    }
#pragma unroll
    for (int it = 0; it < 4; ++it) {
        int flat = it * 256 + t, row = flat >> 3, src = (flat & 7) ^ (row & 7);
        gload_lds16(Bb + (long)row * p.ldb + src * 8, &lB[0][flat * 8]);
    }
    __syncthreads();

    for (int kt = 0; kt < nk; ++kt) {
        const int cur = kt & 1, nxt = cur ^ 1;
        if (kt + 1 < nk) {
            const long kb = (long)(kt + 1) * 64;
#pragma unroll
            for (int it = 0; it < AITS; ++it) {
                int flat = it * 256 + t, row = flat >> 3, src = (flat & 7) ^ (row & 7);
                gload_lds16(Ab + (long)row * p.lda + kb + src * 8, &lA[nxt][flat * 8]);
            }
#pragma unroll
            for (int it = 0; it < 4; ++it) {
                int flat = it * 256 + t, row = flat >> 3, src = (flat & 7) ^ (row & 7);
                gload_lds16(Bb + (long)row * p.ldb + kb + src * 8, &lB[nxt][flat * 8]);
            }
        }
#pragma unroll
        for (int kk = 0; kk < 2; ++kk) {
            const int q = kk * 4 + quad;
            short8 aF[MW], bF[4];
#pragma unroll
            for (int mi = 0; mi < MW; mi++) {
                int row = wm + mi * 16 + fr;
                aF[mi] = *(const short8*)&lA[cur][row * 64 + (q ^ (row & 7)) * 8];
            }
#pragma unroll
            for (int ni = 0; ni < 4; ni++) {
                int row = wn + ni * 16 + fr;
                bF[ni] = *(const short8*)&lB[cur][row * 64 + (q ^ (row & 7)) * 8];
            }
#pragma unroll
            for (int mi = 0; mi < MW; mi++)
#pragma unroll
                for (int ni = 0; ni < 4; ni++)
                    acc[mi][ni] = __builtin_amdgcn_mfma_f32_16x16x32_bf16(
                        aF[mi], bF[ni], acc[mi][ni], 0, 0, 0);
        }
        __syncthreads();
    }

    // EPI3: hoist per-row sigmoid
    float sgv[MW][4];
    if (EPI == 3) {
#pragma unroll
        for (int mi = 0; mi < MW; mi++)
#pragma unroll
            for (int r = 0; r < 4; r++) {
                long row = m0 + wm + mi * 16 + quad * 4 + r;
                sgv[mi][r] = fsig(p.gate_pre[row * 8 + z] + bf2f(p.bgate[z]));
            }
    }

    // Epilogue: D row = quad*4+reg, col = lane&15
#pragma unroll
    for (int mi = 0; mi < MW; mi++) {
#pragma unroll
        for (int ni = 0; ni < 4; ni++) {
            const int mg = m0 + wm + mi * 16 + quad * 4;
            const int ng = n0 + wn + ni * 16 + fr;
#pragma unroll
            for (int r = 0; r < 4; r++) {
                float v = acc[mi][ni][r];
                const long row = mg + r;
                if (EPI == 1) {        // tanh(acc+add+bias) -> bf16   [link->fhs]
                    float ad = bf2f(p.add[z * p.addOff + row * p.ldadd + ng]);
                    v = ftanh(v + ad + bf2f(p.bias[p.biasOff[z] + ng]));
                    ((u16*)p.C)[p.cOff[z] + row * p.ldc + ng] = f2bf(v);
                } else if (EPI == 3) { // sig(gate)*tanh(acc+bias)     [upd]
                    v = ftanh(v + bf2f(p.bias[p.biasOff[z] + ng])) * sgv[mi][r];
                    ((u16*)p.C)[p.cOff[z] + row * p.ldc + ng] = f2bf(v);
                } else if (EPI == 4) { // encode mix: h_b, summ_b, h(f32)
                    v = ftanh(v + bf2f(p.bias[ng]));
                    u16 b = f2bf(v);
                    ((u16*)p.C)[row * 512 + ng] = b;
                    p.C3[row * 512 + ng] = b;
                    p.C2[row * 512 + ng] = v;
                } else if (EPI == 6) { // (acc+bias) -> bf16            [cin]
                    v = v + bf2f(p.bias[p.biasOff[z] + ng]);
                    ((u16*)p.C)[p.cOff[z] + row * p.ldc + ng] = f2bf(v);
                } else {               // EPI 7: tanh(acc+add) -> bf16  [f0]
                    float ad = bf2f(p.add[row * p.ldadd + ng]);
                    v = ftanh(v + ad);
                    ((u16*)p.C)[row * p.ldc + ng] = f2bf(v);
                }
            }
        }
    }
}

// ---------------------------------------------------------------------------
// Fused GRU-GEMM (R9 tiling: 64 b x s x 128 w, BK=32), but A-fragments live
// in REGISTERS loaded directly from global in MFMA A-layout
// (A[m=lane&15][k=quad*8+j]) and software-pipelined across the barrier.
// L1 (32KB >> 4KB/kt) serves the 4x inter-wave redundancy. LDS = W only,
// 48 KB; A is out of the barrier-coupled vmcnt path entirely.
// W swizzle f(row)=(row>>1)&3 (R9-verified conflict-free).
// ---------------------------------------------------------------------------
struct GGP {
    const u16* fhs_in;    // [b][s][1024]  (feats | hs_b)
    u16* fhs_out;         // write hs_b' at [b][s][512+w]
    const u16* Wcat;      // [s][1536][1024]
    const u16* b_ih;      // [s][1536]
    const u16* b_hh;      // [s][1536]
    u16* prism;           // [b][s][512]
    float* gate_pre;      // [b][8]  (atomicAdd, pre-zeroed)
    const u16* Wg;        // [s][512]
    const u16* phase;     // [s][512]
    const u16* pgain;     // [s][512]
};

__global__ __launch_bounds__(256) void grug_k(GGP p) {
    __shared__ __align__(16) u16 sW[2][3][128 * 32];    // 48 KB
    const int t    = threadIdx.x;
    const int lane = t & 63;
    const int wv   = t >> 6;
    const int s    = blockIdx.x >> 2;
    const int w0   = (blockIdx.x & 3) * 128;
    const int m0   = blockIdx.y * 64;
    const int fr   = lane & 15;
    const int quad = lane >> 4;
    const int wn   = wv * 32;          // wave's 32-col n-range

    const u16* Ab = p.fhs_in + (long)m0 * 8192 + s * 1024;
    const u16* Wb = p.Wcat + (long)s * 1536 * 1024;

    f32x4 acc[4][4][2];   // [q: r,z,inn,hn][mi][ni]
#pragma unroll
    for (int q = 0; q < 4; q++)
#pragma unroll
        for (int mi = 0; mi < 4; mi++)
#pragma unroll
            for (int ni = 0; ni < 2; ni++) acc[q][mi][ni] = (f32x4){0.f,0.f,0.f,0.f};

    auto stageW = [&](int buf, long kb) {
#pragma unroll
        for (int q = 0; q < 3; q++)
#pragma unroll
            for (int it = 0; it < 2; ++it) {
                int flat = it * 256 + t, row = flat >> 2, src = (flat & 3) ^ ((row >> 1) & 3);
                long g = (long)(q * 512 + w0 + row);
                gload_lds16(Wb + g * 1024 + kb + src * 8, &sW[buf][q][flat * 8]);
            }
    };
    // A in MFMA A-operand layout: lane(fr,quad) -> row fr(+16mi), k quad*8..+7
    const u16* Abase = Ab + (long)fr * 8192 + quad * 8;

    short8 aF[4], aN[4];
#pragma unroll
    for (int mi = 0; mi < 4; mi++)
        aF[mi] = *(const short8*)(Abase + (long)mi * 16 * 8192);
    stageW(0, 0);
    __syncthreads();

    for (int kt = 0; kt < 32; ++kt) {
        const int cur = kt & 1, nxt = cur ^ 1;
        if (kt + 1 < 32) {
            const long kb = (long)(kt + 1) * 32;
#pragma unroll
            for (int mi = 0; mi < 4; mi++)
                aN[mi] = *(const short8*)(Abase + (long)mi * 16 * 8192 + kb);
            stageW(nxt, kb);
        }
        const int qsel = (kt < 16) ? 2 : 3;   // inn (k<512) vs hn (k>=512)
        short8 bF[3][2];
#pragma unroll
        for (int q = 0; q < 3; q++)
#pragma unroll
            for (int ni = 0; ni < 2; ni++) {
                int row = wn + ni * 16 + fr;
                bF[q][ni] = *(const short8*)&sW[cur][q][row * 32 + ((quad ^ ((row >> 1) & 3)) & 3) * 8];
            }
#pragma unroll
        for (int mi = 0; mi < 4; mi++)
#pragma unroll
            for (int ni = 0; ni < 2; ni++) {
                acc[0][mi][ni] = __builtin_amdgcn_mfma_f32_16x16x32_bf16(aF[mi], bF[0][ni], acc[0][mi][ni], 0, 0, 0);
                acc[1][mi][ni] = __builtin_amdgcn_mfma_f32_16x16x32_bf16(aF[mi], bF[1][ni], acc[1][mi][ni], 0, 0, 0);
                if (qsel == 2)
                    acc[2][mi][ni] = __builtin_amdgcn_mfma_f32_16x16x32_bf16(aF[mi], bF[2][ni], acc[2][mi][ni], 0, 0, 0);
                else
                    acc[3][mi][ni] = __builtin_amdgcn_mfma_f32_16x16x32_bf16(aF[mi], bF[2][ni], acc[3][mi][ni], 0, 0, 0);
            }
        __syncthreads();
#pragma unroll
        for (int mi = 0; mi < 4; mi++) aF[mi] = aN[mi];
    }

    // Epilogue: ni-outer; per-column params loaded once.
    const u16* bih = p.b_ih + (long)s * 1536;
    const u16* bhh = p.b_hh + (long)s * 1536;
    float gp[4][4];
#pragma unroll
    for (int mi = 0; mi < 4; mi++)
#pragma unroll
        for (int r = 0; r < 4; r++) gp[mi][r] = 0.f;

#pragma unroll
    for (int ni = 0; ni < 2; ni++) {
        const int col = w0 + wn + ni * 16 + fr;          // w in [0,512)
        const float br  = bf2f(bih[col])        + bf2f(bhh[col]);
        const float bz  = bf2f(bih[512 + col])  + bf2f(bhh[512 + col]);
        const float bin = bf2f(bih[1024 + col]);
        const float bhn = bf2f(bhh[1024 + col]);
        const float ph  = bf2f(p.phase[s * 512 + col]);
        const float gain = fsoftplus(bf2f(p.pgain[s * 512 + col]));
        const float wg  = bf2f(p.Wg[s * 512 + col]);
#pragma unroll
        for (int mi = 0; mi < 4; mi++) {
#pragma unroll
            for (int r = 0; r < 4; r++) {
                const long b = m0 + mi * 16 + quad * 4 + r;
                float rv = fsig(acc[0][mi][ni][r] + br);
                float zv = fsig(acc[1][mi][ni][r] + bz);
                float nv = ftanh(acc[2][mi][ni][r] + bin + rv * (acc[3][mi][ni][r] + bhn));
                float hold = bf2f(p.fhs_in[b * 8192 + s * 1024 + 512 + col]);
                float hv = (1.f - zv) * nv + zv * hold;
                p.fhs_out[b * 8192 + s * 1024 + 512 + col] = f2bf(hv);
                float c = __cosf(hv + ph);
                p.prism[b * 4096 + s * 512 + col] = f2bf(c * c * gain);
                gp[mi][r] += wg * hv;
            }
        }
    }
#pragma unroll
    for (int m = 1; m < 16; m <<= 1)
#pragma unroll
        for (int mi = 0; mi < 4; mi++)
#pragma unroll
            for (int r = 0; r < 4; r++) gp[mi][r] += __shfl_xor(gp[mi][r], m, 64);
    if (fr == 0) {
#pragma unroll
        for (int mi = 0; mi < 4; mi++)
#pragma unroll
            for (int r = 0; r < 4; r++) {
                long b = m0 + mi * 16 + quad * 4 + r;
                atomicAdd(&p.gate_pre[b * 8 + s], gp[mi][r]);
            }
    }
}

// ---------------------------------------------------------------------------
// Encode: masked mean / masked max / last token -> cat [B,1536]
// ---------------------------------------------------------------------------
__global__ __launch_bounds__(256) void encode_k(const int* __restrict__ x,
                                                const u16* __restrict__ embed,
                                                u16* __restrict__ cat) {
    __shared__ int toks[128];
    __shared__ int cnt_s;
    const int b = blockIdx.x, t = threadIdx.x;
    if (t < 128) toks[t] = x[b * 128 + t];
    __syncthreads();
    if (t == 0) {
        int c = 0;
        for (int l = 0; l < 128; l++) c += (toks[l] != 0);
        cnt_s = c;
    }
    __syncthreads();
    const int cnt = cnt_s;
    const int lastTok = toks[cnt > 0 ? cnt - 1 : 0];
    for (int w = t; w < 512; w += 256) {
        float sum = 0.f, mx = -10000.f;
        for (int l = 0; l < 128; l++) {
            int tok = toks[l];
            if (tok != 0) {
                float e = bf2f(embed[tok * 512 + w]);
                sum += e;
                mx = fmaxf(mx, e);
            }
        }
        float mean = sum / (float)(cnt > 0 ? cnt : 1);
        float last = bf2f(embed[lastTok * 512 + w]);
        cat[(long)b * 1536 + w]        = f2bf(mean);
        cat[(long)b * 1536 + 512 + w]  = f2bf(mx);
        cat[(long)b * 1536 + 1024 + w] = f2bf(last);
    }
}

// ---------------------------------------------------------------------------
// delta = sum_s upd / sqrt(S);  h = tanh(h*decay + delta); h_b = bf16(h)
// ---------------------------------------------------------------------------
__global__ __launch_bounds__(256) void hupd_k(const u16* __restrict__ upd,
                                              float* __restrict__ h,
                                              u16* __restrict__ h_b,
                                              const u16* __restrict__ decay_p) {
    const int idx = blockIdx.x * 256 + threadIdx.x;
    const int b = idx >> 9, w = idx & 511;
    const long base = (long)b * 4096 + w;
    float dsum = 0.f;
#pragma unroll
    for (int s = 0; s < 8; s++) dsum += bf2f(upd[base + s * 512]);
    const float decay = fsig(bf2f(decay_p[0]));
    const float hv = ftanh(h[idx] * decay + dsum * 0.35355339059327373f);
    h[idx] = hv;
    h_b[idx] = f2bf(hv);
}

// ---------------------------------------------------------------------------
// Final head; output dtype follows detected input dtype.
// ---------------------------------------------------------------------------
__global__ __launch_bounds__(64) void out_k(const float* __restrict__ h,
                                            const u16* __restrict__ Wout,
                                            const u16* __restrict__ bout,
                                            void* __restrict__ out,
                                            const int* __restrict__ flag) {
    const int b = blockIdx.x, lane = threadIdx.x;
    const int isbf = *flag;
    for (int j = 0; j < 10; j++) {
        float p = 0.f;
#pragma unroll
        for (int k = 0; k < 8; k++) {
            int w = lane + k * 64;
            p += h[(long)b * 512 + w] * bf2f(Wout[j * 512 + w]);
        }
#pragma unroll
        for (int off = 32; off; off >>= 1) p += __shfl_down(p, off, 64);
        if (lane == 0) {
            float val = p + bf2f(bout[j]);
            if (isbf) ((u16*)out)[b * 10 + j] = f2bf(val);
            else      ((float*)out)[b * 10 + j] = val;
        }
    }
}

// ---------------------------------------------------------------------------
extern "C" void kernel_launch(void* const* d_in, const int* in_sizes, int n_in,
                              void* d_out, int out_size, void* d_ws, size_t ws_size,
                              hipStream_t stream) {
    (void)n_in; (void)out_size; (void)ws_size;
    const int* x = (const int*)d_in[0];

    char* pp = (char*)d_ws;
    auto carve = [&](size_t n) { char* r = pp; pp += (n + 255) & ~(size_t)255; return (void*)r; };

    // canonical bf16 parameter block (~44 MB)
    CT ct;
    size_t ctot = 0;
    for (int i = 0; i < 20; i++) {
        ct.src[i] = d_in[i + 1];
        ct.n[i]   = in_sizes[i + 1];
        ct.off[i] = (int)ctot;
        ctot += ((size_t)in_sizes[i + 1] + 15) & ~(size_t)15;
    }
    u16* canon = (u16*)carve(ctot * 2);
    const u16* embed  = canon + ct.off[0];
    const u16* W_mix  = canon + ct.off[1];
    const u16* b_mix  = canon + ct.off[2];
    const u16* W_in   = canon + ct.off[3];
    const u16* b_in   = canon + ct.off[4];
    const u16* W_link = canon + ct.off[5];
    const u16* b_link = canon + ct.off[6];
    const u16* W_ih   = canon + ct.off[7];
    const u16* b_ih   = canon + ct.off[8];
    const u16* W_hh   = canon + ct.off[9];
    const u16* b_hh   = canon + ct.off[10];
    const u16* W_gate = canon + ct.off[11];
    const u16* b_gate = canon + ct.off[12];
    const u16* phase  = canon + ct.off[13];
    const u16* pgain  = canon + ct.off[14];
    const u16* W_delta= canon + ct.off[15];
    const u16* b_delta= canon + ct.off[16];
    const u16* decayp = canon + ct.off[17];
    const u16* W_out  = canon + ct.off[18];
    const u16* b_out  = canon + ct.off[19];

    int*   flag   = (int*)  carve(256);
    u16*   Wcat   = (u16*)  carve((size_t)8 * 1536 * 1024 * 2);  // 25 MB
    u16*   cat    = (u16*)  carve((size_t)1024 * 1536 * 2);
    u16*   h_b    = (u16*)  carve((size_t)1024 * 512 * 2);
    u16*   summ_b = (u16*)  carve((size_t)1024 * 512 * 2);
    float* h      = (float*)carve((size_t)1024 * 512 * 4);
    u16*   cin    = (u16*)  carve((size_t)1024 * 4096 * 2);
    u16*   f0     = (u16*)  carve((size_t)1024 * 4096 * 2);
    u16*   fhs0   = (u16*)  carve((size_t)1024 * 8192 * 2);      // 16 MB
    u16*   fhs1   = (u16*)  carve((size_t)1024 * 8192 * 2);      // 16 MB
    u16*   prism  = (u16*)  carve((size_t)1024 * 4096 * 2);
    u16*   upd    = (u16*)  carve((size_t)1024 * 4096 * 2);
    float* gate_pre = (float*)carve((size_t)1024 * 8 * 4);

    (void)hipMemsetAsync(fhs0, 0, (size_t)1024 * 8192 * 2, stream);
    (void)hipMemsetAsync(fhs1, 0, (size_t)1024 * 8192 * 2, stream);

    detect_k<<<dim3(1), dim3(256), 0, stream>>>((const u16*)d_in[1], flag);
    conv_k<<<dim3(1024), dim3(256), 0, stream>>>(ct, canon, flag);
    pack_k<<<dim3(3072), dim3(256), 0, stream>>>(W_ih, W_hh, Wcat);
    encode_k<<<dim3(1024), dim3(256), 0, stream>>>(x, embed, cat);

    {   // summary = tanh(cat @ W_mix^T + b_mix) -> h_b, summ_b, h
        GP p{}; p.A = cat; p.lda = 1536; p.Bw = W_mix; p.ldb = 1536;
        p.bias = b_mix; p.C = h_b; p.ldc = 512; p.C2 = h; p.C3 = summ_b;
        p.K = 1536; p.nt = 4;
        gemm_k<4, 64><<<dim3(4, 16, 1), dim3(256), 0, stream>>>(p);
    }
    {   // cin = summary @ W_in[:, :, 512:]^T + b_in
        GP p{}; p.A = summ_b; p.lda = 512; p.Bw = W_in + 512; p.ldb = 1024;
        p.bias = b_in; p.C = cin; p.ldc = 4096; p.K = 512; p.nt = 32;
        gemm_k<6, 64><<<dim3(32, 16, 1), dim3(256), 0, stream>>>(p);
    }

    for (int step = 0; step < 12; ++step) {
        u16* fhs_cur = (step & 1) ? fhs1 : fhs0;
        u16* fhs_nxt = (step & 1) ? fhs0 : fhs1;
        {   // f0 = tanh(h @ W_in[:, :, :512]^T + cin)
            GP p{}; p.A = h_b; p.lda = 512; p.Bw = W_in; p.ldb = 1024;
            p.add = cin; p.ldadd = 4096; p.C = f0; p.ldc = 4096;
            p.K = 512; p.nt = 32;
            gemm_k<7, 64><<<dim3(32, 16, 1), dim3(256), 0, stream>>>(p);
        }
        {   // feats = tanh(f0 + prev @ W_link^T + b_link) -> fhs_cur[:, s, 0:512]
            GP p{}; p.A = f0; p.lda = 4096;
            for (int s = 0; s < 8; s++) p.aOff[s] = (long)((s + 7) & 7) * 512;
            p.Bw = W_link; p.ldb = 512;
            for (int s = 0; s < 8; s++) p.bwOff[s] = (long)s * 512 * 512;
            p.bias = b_link;
            for (int s = 0; s < 8; s++) p.biasOff[s] = (long)s * 512;
            p.add = f0; p.ldadd = 4096; p.addOff = 512;
            p.C = fhs_cur; p.ldc = 8192;
            for (int s = 0; s < 8; s++) p.cOff[s] = (long)s * 1024;
            p.K = 512; p.nt = 4;
            gemm_k<1, 64><<<dim3(32, 16, 1), dim3(256), 0, stream>>>(p);
        }
        (void)hipMemsetAsync(gate_pre, 0, (size_t)1024 * 8 * 4, stream);
        {   // fused GRU-GEMM (A-in-registers, 48 KB LDS)
            GGP g{};
            g.fhs_in = fhs_cur; g.fhs_out = fhs_nxt; g.Wcat = Wcat;
            g.b_ih = b_ih; g.b_hh = b_hh; g.prism = prism; g.gate_pre = gate_pre;
            g.Wg = W_gate; g.phase = phase; g.pgain = pgain;
            grug_k<<<dim3(32, 16, 1), dim3(256), 0, stream>>>(g);
        }
        {   // upd = sig(gate)*tanh(prism @ W_delta^T + b_delta) -> bf16
            GP p{}; p.A = prism; p.lda = 4096;
            for (int s = 0; s < 8; s++) p.aOff[s] = (long)s * 512;
            p.Bw = W_delta; p.ldb = 512;
            for (int s = 0; s < 8; s++) p.bwOff[s] = (long)s * 512 * 512;
            p.bias = b_delta;
            for (int s = 0; s < 8; s++) p.biasOff[s] = (long)s * 512;
            p.gate_pre = gate_pre; p.bgate = b_gate;
            p.C = upd; p.ldc = 4096;
            for (int s = 0; s < 8; s++) p.cOff[s] = (long)s * 512;
            p.K = 512; p.nt = 4;
            gemm_k<3, 64><<<dim3(32, 16, 1), dim3(256), 0, stream>>>(p);
        }
        hupd_k<<<dim3(2048), dim3(256), 0, stream>>>(upd, h, h_b, decayp);
    }

    out_k<<<dim3(1024), dim3(64), 0, stream>>>(h, W_out, b_out, d_out, flag);
}